// Round 1
// baseline (111.020 us; speedup 1.0000x reference)
//
#include <hip/hip_runtime.h>
#include <hip/hip_cooperative_groups.h>
#include <math.h>

namespace cg = cooperative_groups;

#define N 384
#define D 256
#define D4 (D/4)
#define A 3
#define GRID (N/A)      // 128 blocks
#define TPB N           // 384 threads = 6 waves; j == threadIdx.x
#define NW (TPB/64)     // 6 waves
#define MARGIN_F 0.3f

// Fused single-dispatch kernel (cooperative launch).
// Phase 1: one block per A=3 anchors, identical math to the verified k_rows.
// grid.sync(), then Phase 2: block 0 reduces the per-row arrays to the scalar
// (identical math to the verified k_final).
__global__ __launch_bounds__(TPB) void k_fused(const float* __restrict__ e,
                                               const int* __restrict__ labels,
                                               float* __restrict__ semi_sum,
                                               int* __restrict__ semi_cnt,
                                               float* __restrict__ hp_arr,
                                               float* __restrict__ mn_arr,
                                               float* __restrict__ rm_arr,
                                               int* __restrict__ pc_arr,
                                               float* __restrict__ out) {
  __shared__ float4 ei[A][D4];      // anchor embeddings (broadcast reads)
  __shared__ float  nrm[N];         // ||e_j||^2, written by thread j
  __shared__ float  row[A][N];      // d[anchor][j]
  __shared__ float  negd[A][N];     // d if negative else sentinel
  __shared__ int    lab[N];
  __shared__ int    poslist[A][N];
  __shared__ int    npos[A];
  __shared__ float  wredf[A][4][NW];   // 0:sum 1:hp 2:mn 3:rm
  __shared__ int    wredi[A][2][NW];   // 0:cnt 1:pc
  // phase-2 scratch (block 0 only)
  __shared__ float  shf[12];
  __shared__ int    shi[6];
  __shared__ float  s_maxd, s_tsum;
  __shared__ int    s_tcnt;

  const int b = blockIdx.x;
  const int t = threadIdx.x;           // == column j
  const int i0 = b * A;

  lab[t] = labels[t];
  if (t < A * D4) {
    int a = t / D4, c = t % D4;
    ei[a][c] = ((const float4*)e)[(size_t)(i0 + a) * D4 + c];
  }
  if (t < A) npos[t] = 0;
  __syncthreads();

  // main loop: this thread's row dot each anchor + its own squared norm
  const float4* ej = (const float4*)(e + (size_t)t * D);
  float4 dv0 = {0,0,0,0}, dv1 = {0,0,0,0}, dv2 = {0,0,0,0}, nv = {0,0,0,0};
#pragma unroll 8
  for (int c = 0; c < D4; ++c) {
    float4 v = ej[c];
    nv.x += v.x*v.x; nv.y += v.y*v.y; nv.z += v.z*v.z; nv.w += v.w*v.w;
    float4 u0 = ei[0][c];
    dv0.x += u0.x*v.x; dv0.y += u0.y*v.y; dv0.z += u0.z*v.z; dv0.w += u0.w*v.w;
    float4 u1 = ei[1][c];
    dv1.x += u1.x*v.x; dv1.y += u1.y*v.y; dv1.z += u1.z*v.z; dv1.w += u1.w*v.w;
    float4 u2 = ei[2][c];
    dv2.x += u2.x*v.x; dv2.y += u2.y*v.y; dv2.z += u2.z*v.z; dv2.w += u2.w*v.w;
  }
  const float nj = (nv.x + nv.y) + (nv.z + nv.w);
  float dots[A];
  dots[0] = (dv0.x + dv0.y) + (dv0.z + dv0.w);
  dots[1] = (dv1.x + dv1.y) + (dv1.z + dv1.w);
  dots[2] = (dv2.x + dv2.y) + (dv2.z + dv2.w);
  nrm[t] = nj;
  __syncthreads();

  const int lj = lab[t];
  float hpv[A], mnv[A], rmv[A];
  int   pcv[A];
#pragma unroll
  for (int a = 0; a < A; ++a) {
    const float ni = nrm[i0 + a];
    float d2 = fmaxf(ni + nj - 2.0f * dots[a], 0.0f);
    float dvv = (d2 > 0.0f) ? sqrtf(d2) : 0.0f;   // ref zmask semantics
    const bool eq    = (lj == lab[i0 + a]);
    const bool ispos = eq && (t != i0 + a);
    row[a][t]  = dvv;
    negd[a][t] = eq ? 1e30f : dvv;   // sentinel never passes validity test
    rmv[a] = dvv;
    mnv[a] = eq ? 1e30f : dvv;
    hpv[a] = ispos ? dvv : 0.0f;     // matches (apf*d).max: 0 if no positives
    pcv[a] = ispos ? 1 : 0;
    if (ispos) { int idx = atomicAdd(&npos[a], 1); poslist[a][idx] = t; }
  }
  __syncthreads();

  const int w = t >> 6;
#pragma unroll
  for (int a = 0; a < A; ++a) {
    // semi-hard: this thread is negative-candidate k==t for every positive j
    const float an = negd[a][t];
    float s = 0.0f;
    int   c = 0;
    const int np = npos[a];
    for (int p = 0; p < np; ++p) {
      const float ap = row[a][poslist[a][p]];   // LDS broadcast
      const float loss = ap - an + MARGIN_F;
      if (an > ap && loss > 0.0f) { s += loss; c++; }
    }
    float hp = hpv[a], mn = mnv[a], rm = rmv[a];
    int   pc = pcv[a];
    for (int off = 32; off; off >>= 1) {
      s  += __shfl_down(s, off);
      c  += __shfl_down(c, off);
      hp  = fmaxf(hp, __shfl_down(hp, off));
      mn  = fminf(mn, __shfl_down(mn, off));
      rm  = fmaxf(rm, __shfl_down(rm, off));
      pc += __shfl_down(pc, off);
    }
    if ((t & 63) == 0) {
      wredf[a][0][w] = s;  wredf[a][1][w] = hp;
      wredf[a][2][w] = mn; wredf[a][3][w] = rm;
      wredi[a][0][w] = c;  wredi[a][1][w] = pc;
    }
  }
  __syncthreads();
  if (t < A) {
    float S = 0.0f, HP = 0.0f, MN = 1e30f, RM = 0.0f;
    int   C = 0, PC = 0;
    for (int ww = 0; ww < NW; ++ww) {
      S += wredf[t][0][ww];
      HP = fmaxf(HP, wredf[t][1][ww]);
      MN = fminf(MN, wredf[t][2][ww]);
      RM = fmaxf(RM, wredf[t][3][ww]);
      C += wredi[t][0][ww];
      PC += wredi[t][1][ww];
    }
    const int i = i0 + t;
    semi_sum[i] = S; semi_cnt[i] = C;
    hp_arr[i] = HP;  mn_arr[i] = MN;
    rm_arr[i] = RM;  pc_arr[i] = PC;
  }

  // ---- grid-wide barrier: all per-row results in global memory ----
  __threadfence();
  cg::this_grid().sync();

  // ---- Phase 2: block 0 reduces to the final scalar (old k_final) ----
  if (b == 0) {
    float s  = semi_sum[t];
    float rm = rm_arr[t];
    int   c  = semi_cnt[t];
    for (int off = 32; off; off >>= 1) {
      s += __shfl_down(s, off);
      rm = fmaxf(rm, __shfl_down(rm, off));
      c += __shfl_down(c, off);
    }
    const int wv = t >> 6;
    if ((t & 63) == 0) { shf[wv] = s; shf[6 + wv] = rm; shi[wv] = c; }
    __syncthreads();
    if (t == 0) {
      float ts = 0.0f, md = 0.0f; int tc = 0;
      for (int ww = 0; ww < 6; ++ww) { ts += shf[ww]; md = fmaxf(md, shf[6 + ww]); tc += shi[ww]; }
      s_tsum = ts; s_tcnt = tc; s_maxd = md;
    }
    __syncthreads();
    const float maxd = s_maxd;

    // hard loss per row: hardest_neg = min(min_neg, max_d)
    float hp   = hp_arr[t];
    float mnv2 = mn_arr[t];
    int   pcv2 = pc_arr[t];
    float hn   = fminf(mnv2, maxd);
    float tl   = fmaxf(hp - hn + MARGIN_F, 0.0f);
    int   vld  = (pcv2 > 0) ? 1 : 0;
    float contrib = vld ? tl : 0.0f;
    for (int off = 32; off; off >>= 1) {
      contrib += __shfl_down(contrib, off);
      vld += __shfl_down(vld, off);
    }
    __syncthreads();   // protect shf/shi reuse
    if ((t & 63) == 0) { shf[wv] = contrib; shi[wv] = vld; }
    __syncthreads();
    if (t == 0) {
      float hs = 0.0f; int vc = 0;
      for (int ww = 0; ww < 6; ++ww) { hs += shf[ww]; vc += shi[ww]; }
      float semi = s_tsum / fmaxf((float)s_tcnt, 1.0f);
      float hard = (vc > 0) ? (hs / (float)vc) : 0.0f;
      out[0] = (s_tcnt > 0) ? semi : hard;
    }
  }
}

extern "C" void kernel_launch(void* const* d_in, const int* in_sizes, int n_in,
                              void* d_out, int out_size, void* d_ws, size_t ws_size,
                              hipStream_t stream) {
  (void)in_sizes; (void)n_in; (void)out_size; (void)ws_size;
  const float* e      = (const float*)d_in[0];
  const int*   labels = (const int*)d_in[1];
  float*       out    = (float*)d_out;

  float* ws       = (float*)d_ws;
  float* semi_sum = ws;              // 384 f32
  float* hp_arr   = ws + N;          // 384 f32
  float* mn_arr   = ws + 2 * N;      // 384 f32
  float* rm_arr   = ws + 3 * N;      // 384 f32
  int*   semi_cnt = (int*)(ws + 4 * N);
  int*   pc_arr   = (int*)(ws + 5 * N);

  void* args[] = {(void*)&e, (void*)&labels, (void*)&semi_sum, (void*)&semi_cnt,
                  (void*)&hp_arr, (void*)&mn_arr, (void*)&rm_arr, (void*)&pc_arr,
                  (void*)&out};
  hipLaunchCooperativeKernel((const void*)k_fused, dim3(GRID), dim3(TPB),
                             args, 0, stream);
}

// Round 2
// 70.936 us; speedup vs baseline: 1.5651x; 1.5651x over previous
//
#include <hip/hip_runtime.h>
#include <math.h>

#define N 384
#define D 256
#define D4 (D/4)
#define A 3
#define GRID (N/A)      // 128 blocks
#define TPB N           // 384 threads = 6 waves; j == threadIdx.x
#define NW (TPB/64)     // 6 waves
#define MARGIN_F 0.3f

// K1: one block per A=3 anchors. Coalesced load phase: each wave owns 64 rows;
// 16 lanes cooperate per row (contiguous 256B chunks), segment-shfl reduce.
// Downstream per-column logic identical to the verified round-0 kernel.
__global__ __launch_bounds__(TPB) void k_rows(const float* __restrict__ e,
                                              const int* __restrict__ labels,
                                              float* __restrict__ semi_sum,
                                              int* __restrict__ semi_cnt,
                                              float* __restrict__ hp_arr,
                                              float* __restrict__ mn_arr,
                                              float* __restrict__ rm_arr,
                                              int* __restrict__ pc_arr) {
  __shared__ float4 ei[A][D4];      // anchor embeddings (broadcast reads)
  __shared__ float  nrm[N];         // ||e_j||^2
  __shared__ float  sdot[N][A];     // dot(e_j, anchor_a); stride 3 -> conflict-free
  __shared__ float  row[A][N];      // d[anchor][j]
  __shared__ float  negd[A][N];     // d if negative else sentinel
  __shared__ int    lab[N];
  __shared__ int    poslist[A][N];
  __shared__ int    npos[A];
  __shared__ float  wredf[A][4][NW];   // 0:sum 1:hp 2:mn 3:rm
  __shared__ int    wredi[A][2][NW];   // 0:cnt 1:pc

  const int b = blockIdx.x;
  const int t = threadIdx.x;
  const int i0 = b * A;

  lab[t] = labels[t];
  if (t < A * D4) {
    int a = t / D4, c = t % D4;
    ei[a][c] = ((const float4*)e)[(size_t)(i0 + a) * D4 + c];
  }
  if (t < A) npos[t] = 0;
  __syncthreads();

  // ---- Phase L: coalesced loads + dots ----
  // wave w handles rows [w*64, w*64+64). Within a pass: 4 rows, 16 lanes each.
  {
    const int w   = t >> 6;
    const int ln  = t & 63;
    const int r4  = ln >> 4;      // which of 4 rows this lane helps with
    const int l16 = ln & 15;      // position within the row's 16-lane team
    const float4* e4 = (const float4*)e;
    for (int p = 0; p < 16; ++p) {
      const int j = w * 64 + p * 4 + r4;
      float nj = 0.f, d0 = 0.f, d1 = 0.f, d2 = 0.f;
#pragma unroll
      for (int k = 0; k < 4; ++k) {
        const int c = l16 + k * 16;                 // float4 index in row
        const float4 v  = e4[(size_t)j * D4 + c];   // 16 lanes -> 256B contiguous
        const float4 u0 = ei[0][c];
        const float4 u1 = ei[1][c];
        const float4 u2 = ei[2][c];
        nj += v.x*v.x + v.y*v.y + v.z*v.z + v.w*v.w;
        d0 += u0.x*v.x + u0.y*v.y + u0.z*v.z + u0.w*v.w;
        d1 += u1.x*v.x + u1.y*v.y + u1.z*v.z + u1.w*v.w;
        d2 += u2.x*v.x + u2.y*v.y + u2.z*v.z + u2.w*v.w;
      }
#pragma unroll
      for (int off = 8; off; off >>= 1) {
        nj += __shfl_down(nj, off, 16);
        d0 += __shfl_down(d0, off, 16);
        d1 += __shfl_down(d1, off, 16);
        d2 += __shfl_down(d2, off, 16);
      }
      if (l16 == 0) {
        nrm[j] = nj;
        sdot[j][0] = d0; sdot[j][1] = d1; sdot[j][2] = d2;
      }
    }
  }
  __syncthreads();

  // ---- per-column phase (verbatim round-0 logic; inputs now from LDS) ----
  const int lj = lab[t];
  const float nj = nrm[t];
  float dots[A];
  dots[0] = sdot[t][0]; dots[1] = sdot[t][1]; dots[2] = sdot[t][2];

  float hpv[A], mnv[A], rmv[A];
  int   pcv[A];
#pragma unroll
  for (int a = 0; a < A; ++a) {
    const float ni = nrm[i0 + a];
    float d2 = fmaxf(ni + nj - 2.0f * dots[a], 0.0f);
    float dvv = (d2 > 0.0f) ? sqrtf(d2) : 0.0f;   // ref zmask semantics
    const bool eq    = (lj == lab[i0 + a]);
    const bool ispos = eq && (t != i0 + a);
    row[a][t]  = dvv;
    negd[a][t] = eq ? 1e30f : dvv;   // sentinel never passes validity test
    rmv[a] = dvv;
    mnv[a] = eq ? 1e30f : dvv;
    hpv[a] = ispos ? dvv : 0.0f;     // matches (apf*d).max: 0 if no positives
    pcv[a] = ispos ? 1 : 0;
    if (ispos) { int idx = atomicAdd(&npos[a], 1); poslist[a][idx] = t; }
  }
  __syncthreads();

  const int w = t >> 6;
#pragma unroll
  for (int a = 0; a < A; ++a) {
    // semi-hard: this thread is negative-candidate k==t for every positive j
    const float an = negd[a][t];
    float s = 0.0f;
    int   c = 0;
    const int np = npos[a];
    for (int p = 0; p < np; ++p) {
      const float ap = row[a][poslist[a][p]];   // LDS broadcast
      const float loss = ap - an + MARGIN_F;
      if (an > ap && loss > 0.0f) { s += loss; c++; }
    }
    float hp = hpv[a], mn = mnv[a], rm = rmv[a];
    int   pc = pcv[a];
    for (int off = 32; off; off >>= 1) {
      s  += __shfl_down(s, off);
      c  += __shfl_down(c, off);
      hp  = fmaxf(hp, __shfl_down(hp, off));
      mn  = fminf(mn, __shfl_down(mn, off));
      rm  = fmaxf(rm, __shfl_down(rm, off));
      pc += __shfl_down(pc, off);
    }
    if ((t & 63) == 0) {
      wredf[a][0][w] = s;  wredf[a][1][w] = hp;
      wredf[a][2][w] = mn; wredf[a][3][w] = rm;
      wredi[a][0][w] = c;  wredi[a][1][w] = pc;
    }
  }
  __syncthreads();
  if (t < A) {
    float S = 0.0f, HP = 0.0f, MN = 1e30f, RM = 0.0f;
    int   C = 0, PC = 0;
    for (int ww = 0; ww < NW; ++ww) {
      S += wredf[t][0][ww];
      HP = fmaxf(HP, wredf[t][1][ww]);
      MN = fminf(MN, wredf[t][2][ww]);
      RM = fmaxf(RM, wredf[t][3][ww]);
      C += wredi[t][0][ww];
      PC += wredi[t][1][ww];
    }
    const int i = i0 + t;
    semi_sum[i] = S; semi_cnt[i] = C;
    hp_arr[i] = HP;  mn_arr[i] = MN;
    rm_arr[i] = RM;  pc_arr[i] = PC;
  }
}

// K2: one wave, barrier-free; each thread owns 6 rows (stride-64 coalesced).
__global__ __launch_bounds__(64) void k_final(const float* __restrict__ semi_sum,
                                              const int* __restrict__ semi_cnt,
                                              const float* __restrict__ hp_arr,
                                              const float* __restrict__ mn_arr,
                                              const float* __restrict__ rm_arr,
                                              const int* __restrict__ pc_arr,
                                              float* __restrict__ out) {
  const int t = threadIdx.x;    // 0..63

  // pass 1: global semi sum/count + max distance
  float S = 0.0f, RM = 0.0f;
  int   C = 0;
#pragma unroll
  for (int i = 0; i < 6; ++i) {
    const int r = t + 64 * i;
    S += semi_sum[r];
    RM = fmaxf(RM, rm_arr[r]);
    C += semi_cnt[r];
  }
  for (int off = 32; off; off >>= 1) {
    S  += __shfl_down(S, off);
    RM  = fmaxf(RM, __shfl_down(RM, off));
    C  += __shfl_down(C, off);
  }
  S  = __shfl(S, 0);
  RM = __shfl(RM, 0);
  C  = __shfl(C, 0);
  const float maxd = RM;

  // pass 2: hard loss per row, hardest_neg = min(min_neg, max_d)
  float hs = 0.0f;
  int   vc = 0;
#pragma unroll
  for (int i = 0; i < 6; ++i) {
    const int r = t + 64 * i;
    const float hp = hp_arr[r];
    const float mn = mn_arr[r];
    const int   pc = pc_arr[r];
    const float hn = fminf(mn, maxd);
    const float tl = fmaxf(hp - hn + MARGIN_F, 0.0f);
    if (pc > 0) { hs += tl; vc += 1; }
  }
  for (int off = 32; off; off >>= 1) {
    hs += __shfl_down(hs, off);
    vc += __shfl_down(vc, off);
  }
  if (t == 0) {
    const float semi = S / fmaxf((float)C, 1.0f);
    const float hard = (vc > 0) ? (hs / (float)vc) : 0.0f;
    out[0] = (C > 0) ? semi : hard;
  }
}

extern "C" void kernel_launch(void* const* d_in, const int* in_sizes, int n_in,
                              void* d_out, int out_size, void* d_ws, size_t ws_size,
                              hipStream_t stream) {
  (void)in_sizes; (void)n_in; (void)out_size; (void)ws_size;
  const float* e      = (const float*)d_in[0];
  const int*   labels = (const int*)d_in[1];
  float*       out    = (float*)d_out;

  float* ws       = (float*)d_ws;
  float* semi_sum = ws;              // 384 f32
  float* hp_arr   = ws + N;          // 384 f32
  float* mn_arr   = ws + 2 * N;      // 384 f32
  float* rm_arr   = ws + 3 * N;      // 384 f32
  int*   semi_cnt = (int*)(ws + 4 * N);
  int*   pc_arr   = (int*)(ws + 5 * N);

  k_rows<<<GRID, TPB, 0, stream>>>(e, labels, semi_sum, semi_cnt,
                                   hp_arr, mn_arr, rm_arr, pc_arr);
  k_final<<<1, 64, 0, stream>>>(semi_sum, semi_cnt, hp_arr, mn_arr, rm_arr,
                                pc_arr, out);
}